// Round 1
// baseline (896.731 us; speedup 1.0000x reference)
//
#include <hip/hip_runtime.h>
#include <math.h>

// RNN-T transducer loss (forward only, mean reduction).
// B=16, T<=200, U+1<=101 columns, vocab=512, blank=0.
// Strategy: one block per batch item; anti-diagonal wavefront over the
// (t,u) lattice. Thread u owns column u. One __syncthreads per diagonal
// with an LDS double buffer carrying the previous diagonal's alpha.
// Global loads (blank + gathered label log-prob per cell) are independent
// of the recurrence, so they are prefetched DEPTH diagonals ahead.

#define BATCH 16
#define TMAX  200
#define UMAX  101   // columns u = 0..100
#define VOC   512
#define NTHR  128
#define DEPTH 4

__device__ __forceinline__ float lse2(float a, float b) {
    float m = fmaxf(a, b);
    float r = m + __logf(__expf(a - m) + __expf(b - m));
    return (m == -INFINITY) ? -INFINITY : r;  // guard NaN from (-inf) - (-inf)
}

__global__ __launch_bounds__(NTHR) void rnnt_fwd_kernel(
    const float* __restrict__ lp,      // [B, TMAX, UMAX, VOC] log-softmaxed
    const int*   __restrict__ labels,  // [B, UMAX-1]
    const int*   __restrict__ Tarr,    // [B]
    const int*   __restrict__ Uarr,    // [B]
    float*       __restrict__ out)     // [1], pre-zeroed
{
    const int b = blockIdx.x;
    const int u = threadIdx.x;

    __shared__ float As[2][NTHR];  // previous/current diagonal alpha

    const int Tb = Tarr[b];
    const int Ub = Uarr[b];
    const float* lpb = lp + (size_t)b * TMAX * UMAX * VOC;

    // label feeding emit[t, u-1] (used by the cell in column u)
    int labm1 = 0;
    if (u >= 1 && u <= UMAX - 1) labm1 = labels[b * (UMAX - 1) + (u - 1)];

    const float NEG = -INFINITY;
    float A = (u == 0) ? 0.0f : NEG;   // diagonal 0: alpha[0,0] = 0
    As[0][u] = A;
    __syncthreads();

    const int dmax = Tb - 1 + Ub;      // last diagonal holding (Tb-1, Ub)
    const bool loader = (u <= Ub);

    // loads for diagonal d: blk[t-1, u] and emit[t, u-1], t = d - u.
    // Indices clamped into the tensor; invalid terms are masked at compute.
    float pb[DEPTH], pe[DEPTH];
    auto ld = [&](int d, float& vb, float& ve) {
        int t   = d - u;
        int tb_ = min(max(t - 1, 0), TMAX - 1);
        int te_ = min(max(t,     0), TMAX - 1);
        int ue_ = max(u - 1, 0);
        if (loader) {
            vb = lpb[((size_t)tb_ * UMAX + u)   * VOC];           // blank
            ve = lpb[((size_t)te_ * UMAX + ue_) * VOC + labm1];   // label
        } else { vb = 0.0f; ve = 0.0f; }
    };

#pragma unroll
    for (int j = 0; j < DEPTH; ++j) {
        int d = 1 + j;
        ld(d <= dmax ? d : dmax, pb[j], pe[j]);
    }

    for (int dbase = 1; dbase <= dmax; dbase += DEPTH) {
        float cb[DEPTH], ce[DEPTH];
#pragma unroll
        for (int j = 0; j < DEPTH; ++j) { cb[j] = pb[j]; ce[j] = pe[j]; }
        // issue next group's loads before computing this group
#pragma unroll
        for (int j = 0; j < DEPTH; ++j) {
            int dn = dbase + DEPTH + j;
            ld(dn <= dmax ? dn : dmax, pb[j], pe[j]);
        }
#pragma unroll
        for (int j = 0; j < DEPTH; ++j) {
            const int d = dbase + j;
            if (d > dmax) break;  // d is block-uniform -> barrier-safe
            const int t = d - u;
            const bool active = (u <= Ub) && (u <= d) && (t <= Tb - 1);
            const float left  = As[(d - 1) & 1][(u == 0) ? 0 : (u - 1)];
            const float top   = (active && t >= 1) ? (A    + cb[j]) : NEG;
            const float lft   = (active && u >= 1) ? (left + ce[j]) : NEG;
            const float An    = active ? lse2(top, lft) : NEG;
            As[d & 1][u] = An;
            A = An;
            __syncthreads();
        }
    }

    // thread u == Ub holds alpha[Tb-1, Ub] after diagonal dmax
    if (u == Ub) {
        const float blk_fin = lpb[((size_t)(Tb - 1) * UMAX + Ub) * VOC];
        atomicAdd(out, -(A + blk_fin) * (1.0f / BATCH));
    }
}

extern "C" void kernel_launch(void* const* d_in, const int* in_sizes, int n_in,
                              void* d_out, int out_size, void* d_ws, size_t ws_size,
                              hipStream_t stream) {
    const float* lp     = (const float*)d_in[0];
    const int*   labels = (const int*)d_in[1];
    const int*   Tarr   = (const int*)d_in[2];
    const int*   Uarr   = (const int*)d_in[3];
    float* out = (float*)d_out;

    // harness re-poisons d_out with 0xAA before every timed replay
    hipMemsetAsync(out, 0, sizeof(float), stream);
    rnnt_fwd_kernel<<<BATCH, NTHR, 0, stream>>>(lp, labels, Tarr, Uarr, out);
}

// Round 2
// 762.593 us; speedup vs baseline: 1.1759x; 1.1759x over previous
//
#include <hip/hip_runtime.h>
#include <math.h>

// RNN-T transducer loss (forward only, mean reduction), two-phase:
//   Phase 1 (gather_kernel): massively parallel gather of blank/label
//     log-probs from the [B,T,U,512] tensor into compact diagonal-major
//     arrays Dblk[b][d][u], Demit[b][d][u] in d_ws (-INF marks invalid
//     transitions, so phase 2 needs no boundary branches).
//   Phase 2 (sweep_kernel): one wave per batch item; lane i owns columns
//     {2i, 2i+1}. Anti-diagonal wavefront with __shfl_up for the left
//     neighbor -- no LDS, no barriers. Depth-8 register ring prefetch of
//     the coalesced float2 diagonal rows (L2-resident after phase 1).

#define BATCH 16
#define TMAX  200
#define UMAX  101                 // columns u = 0..100
#define VOC   512
#define NDIAG (TMAX + UMAX - 1)   // 300 diagonals
#define PITCH 128                 // padded floats per diagonal row
#define DEPTH 8
#define NEGINF (-INFINITY)

__device__ __forceinline__ float lse2(float a, float b) {
    float m = fmaxf(a, b);
    float r = m + __logf(__expf(a - m) + __expf(b - m));
    return (m == NEGINF) ? NEGINF : r;  // guard NaN from (-inf)-(-inf)
}

// Dblk[b][d][u]  = log P(blank | t-1, u)      with t = d-u  (top transition)
// Demit[b][d][u] = log P(label_{u-1} | t, u-1) with t = d-u  (left transition)
__global__ __launch_bounds__(PITCH) void gather_kernel(
    const float* __restrict__ lp, const int* __restrict__ labels,
    float* __restrict__ Dblk, float* __restrict__ Demit)
{
    const int d = blockIdx.x;
    const int b = blockIdx.y;
    const int u = threadIdx.x;
    const size_t row = ((size_t)b * NDIAG + d) * PITCH + u;

    const int tt = d - u - 1;  // t-1 for blank
    float vb = NEGINF;
    if (u < UMAX && tt >= 0 && tt < TMAX)
        vb = lp[(((size_t)b * TMAX + tt) * UMAX + u) * VOC];

    const int te = d - u;      // t for emit
    float ve = NEGINF;
    if (u >= 1 && u < UMAX && te >= 0 && te < TMAX) {
        const int lab = labels[b * (UMAX - 1) + (u - 1)];
        ve = lp[(((size_t)b * TMAX + te) * UMAX + (u - 1)) * VOC + lab];
    }
    Dblk[row]  = vb;
    Demit[row] = ve;
}

__global__ __launch_bounds__(64) void sweep_kernel(
    const float* __restrict__ Dblk, const float* __restrict__ Demit,
    const float* __restrict__ lp,
    const int* __restrict__ Tarr, const int* __restrict__ Uarr,
    float* __restrict__ out)
{
    const int b    = blockIdx.x;
    const int lane = threadIdx.x;
    const int Tb   = Tarr[b];
    const int Ub   = Uarr[b];
    const int dmax = Tb - 1 + Ub;          // >= 149 always

    const float2* rb = (const float2*)(Dblk  + (size_t)b * NDIAG * PITCH);
    const float2* re = (const float2*)(Demit + (size_t)b * NDIAG * PITCH);

    // alpha for columns c0 = 2*lane, c1 = 2*lane+1 on the previous diagonal
    float A0 = (lane == 0) ? 0.0f : NEGINF;  // alpha[0,0] = 0
    float A1 = NEGINF;

    float2 qb[DEPTH], qe[DEPTH];
#pragma unroll
    for (int j = 0; j < DEPTH; ++j) {
        int d = min(1 + j, dmax);
        qb[j] = rb[d * 64 + lane];
        qe[j] = re[d * 64 + lane];
    }

    for (int dbase = 1; dbase <= dmax; dbase += DEPTH) {
        float2 cb[DEPTH], ce[DEPTH];
#pragma unroll
        for (int j = 0; j < DEPTH; ++j) { cb[j] = qb[j]; ce[j] = qe[j]; }
#pragma unroll
        for (int j = 0; j < DEPTH; ++j) {           // issue next group's loads
            int dn = min(dbase + DEPTH + j, dmax);
            qb[j] = rb[dn * 64 + lane];
            qe[j] = re[dn * 64 + lane];
        }
#pragma unroll
        for (int j = 0; j < DEPTH; ++j) {
            if (dbase + j > dmax) break;            // block-uniform
            // left neighbor of c0 lives in lane-1's c1 (previous diagonal)
            float Aup = __shfl_up(A1, 1);           // lane 0: ce.x = -INF masks it
            float n0 = lse2(A0 + cb[j].x, Aup + ce[j].x);
            float n1 = lse2(A1 + cb[j].y, A0  + ce[j].y);
            A0 = n0; A1 = n1;
        }
    }

    // after diagonal dmax, column Ub holds alpha[Tb-1, Ub]
    if (lane == (Ub >> 1)) {
        float Af   = (Ub & 1) ? A1 : A0;
        float blkf = lp[(((size_t)b * TMAX + (Tb - 1)) * UMAX + Ub) * VOC];
        atomicAdd(out, -(Af + blkf) * (1.0f / BATCH));
    }
}

extern "C" void kernel_launch(void* const* d_in, const int* in_sizes, int n_in,
                              void* d_out, int out_size, void* d_ws, size_t ws_size,
                              hipStream_t stream) {
    const float* lp     = (const float*)d_in[0];
    const int*   labels = (const int*)d_in[1];
    const int*   Tarr   = (const int*)d_in[2];
    const int*   Uarr   = (const int*)d_in[3];
    float* out = (float*)d_out;

    float* Dblk  = (float*)d_ws;                               // 2.46 MB
    float* Demit = Dblk + (size_t)BATCH * NDIAG * PITCH;       // 2.46 MB more

    hipMemsetAsync(out, 0, sizeof(float), stream);             // harness poisons d_out

    dim3 g1(NDIAG, BATCH);
    gather_kernel<<<g1, PITCH, 0, stream>>>(lp, labels, Dblk, Demit);
    sweep_kernel<<<BATCH, 64, 0, stream>>>(Dblk, Demit, lp, Tarr, Uarr, out);
}